// Round 8
// baseline (176.244 us; speedup 1.0000x reference)
//
#include <hip/hip_runtime.h>
#include <hip/hip_bf16.h>

#define B_SIZE 4096
#define D_SIZE 256
#define N_SIZE 8192
#define LOG2E10 14.4269504089f     // 10 * log2(e):  exp(10x) = exp2(x * LOG2E10)

#if __has_builtin(__builtin_amdgcn_exp2f)
#define FAST_EXP2(x) __builtin_amdgcn_exp2f(x)
#else
#define FAST_EXP2(x) __expf((x) * 0.69314718056f)
#endif

typedef __attribute__((ext_vector_type(8))) short short8;
typedef __attribute__((ext_vector_type(4))) short short4v;
typedef __attribute__((ext_vector_type(4))) float floatx4;

// ws layout (bytes):
//       0 : float Sarr[2*8192]        (65536)  per-row full exp-sum (incl diag)
//   65536 : float lossAcc; int ticket (8)
//   66048 : int cnt[128]              (512)
//   66560 : int off[128]              (512)
//   67072 : int idxS[4096]            (16384)  row indices bucketed by class
//   83968 : float g[3][128][256]      (393216) per-class feature sums
//  524288 : bf16 featS|featT0|featT1  (3 x 2MB contiguous)

__device__ __forceinline__ void async16(void* lds, const void* g) {
    __builtin_amdgcn_global_load_lds(
        (const __attribute__((address_space(1))) unsigned int*)g,
        (__attribute__((address_space(3))) unsigned int*)lds, 16, 0, 0);
}

// q in [0,496) -> (R,C) with 0 <= C < R <= 31
__device__ __forceinline__ void pair_from_q(int q, int& R, int& C) {
    int r = (int)((1.0f + sqrtf(1.0f + 8.0f * (float)q)) * 0.5f);
    while (r * (r - 1) / 2 > q) --r;
    while ((r + 1) * r / 2 <= q) ++r;
    R = r; C = q - r * (r - 1) / 2;
}

// Wave-per-row normalize (float4). 3072 blocks x 256. Block 0 also scatters labels.
__global__ void norm_kernel(const float* __restrict__ hs,
                            const float* __restrict__ ht0,
                            const float* __restrict__ ht1,
                            __hip_bfloat16* __restrict__ dst,
                            float* __restrict__ zero_region,
                            const int* __restrict__ labels,
                            int* __restrict__ cnt, int* __restrict__ offv,
                            int* __restrict__ idxS) {
    const int tid = threadIdx.x;
    const int wv  = tid >> 6;
    const int l   = tid & 63;
    const int gid = blockIdx.x * 256 + tid;
    if (gid < 16386) zero_region[gid] = 0.0f;   // Sarr + lossAcc + ticket

    const int row = blockIdx.x * 4 + wv;        // 0..12287
    const float* src = (row < 4096) ? (hs + row * D_SIZE)
                     : (row < 8192) ? (ht0 + (row - 4096) * D_SIZE)
                                    : (ht1 + (row - 8192) * D_SIZE);
    floatx4 x = *reinterpret_cast<const floatx4*>(src + l * 4);
    float ss = x[0] * x[0] + x[1] * x[1] + x[2] * x[2] + x[3] * x[3];
#pragma unroll
    for (int off = 32; off > 0; off >>= 1) ss += __shfl_xor(ss, off);
    float inv = 1.0f / fmaxf(sqrtf(ss), 1e-12f);
    short4v o;
#pragma unroll
    for (int k = 0; k < 4; ++k) {
        __hip_bfloat16 h = __float2bfloat16(x[k] * inv);
        o[k] = *reinterpret_cast<short*>(&h);
    }
    *reinterpret_cast<short4v*>(dst + row * D_SIZE + l * 4) = o;

    if (blockIdx.x == 0) {   // fused label scatter
        __shared__ int h[128], o2[128], ctr[128];
        if (tid < 128) { h[tid] = 0; ctr[tid] = 0; }
        __syncthreads();
        for (int i = tid; i < B_SIZE; i += 256) atomicAdd(&h[labels[i] & 127], 1);
        __syncthreads();
        if (tid == 0) {
            int s = 0;
            for (int c = 0; c < 128; ++c) { o2[c] = s; s += h[c]; }
        }
        __syncthreads();
        for (int i = tid; i < B_SIZE; i += 256) {
            int lab = labels[i] & 127;
            int pos = o2[lab] + atomicAdd(&ctr[lab], 1);
            idxS[pos] = i;
        }
        if (tid < 128) { cnt[tid] = h[tid]; offv[tid] = o2[tid]; }
    }
}

// g_c = sum_{lab_j=c} f_j per set. 384 blocks (set*128+c) x 256 threads.
__global__ void gvec_kernel(const __hip_bfloat16* __restrict__ featBase,
                            const int* __restrict__ cnt,
                            const int* __restrict__ off,
                            const int* __restrict__ idxS,
                            float* __restrict__ gOut) {
    const int c   = blockIdx.x & 127;
    const int set = blockIdx.x >> 7;
    const int tid = threadIdx.x;
    const __hip_bfloat16* f = featBase + set * B_SIZE * D_SIZE;
    __shared__ int sIdx[256];
    const int n = cnt[c], o = off[c];
    float acc = 0.0f;
    for (int base = 0; base < n; base += 256) {
        int m = n - base; if (m > 256) m = 256;
        __syncthreads();
        if (tid < m) sIdx[tid] = idxS[o + base + tid];
        __syncthreads();
        for (int k = 0; k < m; ++k)
            acc += __bfloat162float(f[sIdx[k] * D_SIZE + tid]);
    }
    gOut[set * 32768 + c * 256 + tid] = acc;
}

// Symmetric S-only sim kernel with BALANCED static schedule: 512 blocks.
// Blocks 0..479: two below-diag (R,C,t) tile-pair items. Blocks 480..511:
// one below-diag + two diagonal items. Per item: rows [256R,..), cols [256C,..)
// in 4 LDS-staged 64-col groups (dbuf, MFMA-fragment order, conflict-free).
__global__ __launch_bounds__(256, 2)
void sim_kernel(const __hip_bfloat16* __restrict__ featS,
                const __hip_bfloat16* __restrict__ featT0,
                const __hip_bfloat16* __restrict__ featT1,
                float* __restrict__ Sarr) {
    __shared__ __align__(16) unsigned char sB[2][32768];

    const int tid  = threadIdx.x;
    const int w    = tid >> 6;
    const int l    = tid & 63;
    const int quad = l >> 4;
    const int lcol = l & 15;

    int itemR[3], itemC[3], itemT[3], ni;
    if (blockIdx.x < 480) {
        ni = 2;
#pragma unroll
        for (int k = 0; k < 2; ++k) {
            int m = blockIdx.x * 2 + k;          // 0..959
            pair_from_q(m >> 1, itemR[k], itemC[k]);
            itemT[k] = m & 1;
        }
    } else {
        ni = 3;
        int i = blockIdx.x - 480;                // 0..31
        int m = 960 + i;                         // leftover below-diag items
        pair_from_q(m >> 1, itemR[0], itemC[0]);
        itemT[0] = m & 1;
        itemR[1] = itemC[1] = i; itemT[1] = 0;   // diagonal pair, both teachers
        itemR[2] = itemC[2] = i; itemT[2] = 1;
    }

    for (int it = 0; it < ni; ++it) {
        const int R = itemR[it], C = itemC[it], t = itemT[it];
        const __hip_bfloat16* featT = t ? featT1 : featT0;
        const int row_base = R * 256 + w * 64;
        const int col0 = C * 256;

        // A fragments: 4 row-tiles x 8 k-steps, register resident
        short8 af[4][8];
#pragma unroll
        for (int rt = 0; rt < 4; ++rt) {
            int arow = row_base + rt * 16 + lcol;
            const __hip_bfloat16* ap = (arow < B_SIZE) ? featS + arow * D_SIZE
                                                       : featT + (arow - B_SIZE) * D_SIZE;
#pragma unroll
            for (int ks = 0; ks < 8; ++ks)
                af[rt][ks] = *reinterpret_cast<const short8*>(ap + ks * 32 + quad * 8);
        }

        float Sp[4][4];
#pragma unroll
        for (int rt = 0; rt < 4; ++rt)
#pragma unroll
            for (int r = 0; r < 4; ++r) Sp[rt][r] = 0.0f;

        auto stage = [&](int b, int cb) {
            int tb = cb + w * 16;
            const __hip_bfloat16* cp = (tb < B_SIZE) ? featS + tb * D_SIZE
                                                     : featT + (tb - B_SIZE) * D_SIZE;
            const char* gp = (const char*)cp + (l & 15) * 512 + (l >> 4) * 16;
            unsigned char* lp = &sB[b][w * 8192];
#pragma unroll
            for (int ks = 0; ks < 8; ++ks)
                async16(lp + ks * 1024, gp + ks * 64);
        };

        stage(0, col0);   // safe: others still read buf1 at worst; barrier drains

        for (int g = 0; g < 4; ++g) {
            const int buf = g & 1;
            __syncthreads();                               // drains DMA for buf
            if (g + 1 < 4) stage(buf ^ 1, col0 + (g + 1) * 64);

            const int gcol = col0 + g * 64;
            if (gcol > row_base) continue;                 // above diagonal: skip
            const bool dg = (gcol == row_base);

            float Cp[4] = {0.f, 0.f, 0.f, 0.f};
#pragma unroll
            for (int up = 0; up < 2; ++up) {
                floatx4 acc[2][4];
#pragma unroll
                for (int j = 0; j < 2; ++j)
#pragma unroll
                    for (int rt = 0; rt < 4; ++rt) acc[j][rt] = floatx4{0.f, 0.f, 0.f, 0.f};

#pragma unroll
                for (int ks = 0; ks < 8; ++ks) {
                    short8 bf[2];
#pragma unroll
                    for (int j = 0; j < 2; ++j)
                        bf[j] = *reinterpret_cast<const short8*>(
                            &sB[buf][(up * 2 + j) * 8192 + ks * 1024 + l * 16]);
#pragma unroll
                    for (int j = 0; j < 2; ++j)
#pragma unroll
                        for (int rt = 0; rt < 4; ++rt)
                            acc[j][rt] = __builtin_amdgcn_mfma_f32_16x16x32_bf16(
                                af[rt][ks], bf[j], acc[j][rt], 0, 0, 0);
                }
#pragma unroll
                for (int j = 0; j < 2; ++j)
#pragma unroll
                    for (int rt = 0; rt < 4; ++rt)
#pragma unroll
                        for (int r = 0; r < 4; ++r) {
                            float e = FAST_EXP2(acc[j][rt][r] * LOG2E10);
                            Sp[rt][r] += e;
                            Cp[up * 2 + j] += e;
                        }
            }

            if (!dg) {   // symmetric contribution: col j += sum over tile rows
#pragma unroll
                for (int u = 0; u < 4; ++u) {
                    Cp[u] += __shfl_xor(Cp[u], 16);
                    Cp[u] += __shfl_xor(Cp[u], 32);
                }
                if (quad == 0) {
#pragma unroll
                    for (int u = 0; u < 4; ++u)
                        atomicAdd(&Sarr[t * N_SIZE + gcol + u * 16 + lcol], Cp[u]);
                }
            }
        }

        // row-sum flush
#pragma unroll
        for (int rt = 0; rt < 4; ++rt)
#pragma unroll
            for (int r = 0; r < 4; ++r) {
#pragma unroll
                for (int m = 1; m < 16; m <<= 1) Sp[rt][r] += __shfl_xor(Sp[rt][r], m);
            }
        if (lcol == 0) {
#pragma unroll
            for (int rt = 0; rt < 4; ++rt)
#pragma unroll
                for (int r = 0; r < 4; ++r) {
                    int row = row_base + rt * 16 + quad * 4 + r;
                    atomicAdd(&Sarr[t * N_SIZE + row], Sp[rt][r]);
                }
        }
    }
}

// Per-row stats + final loss. 512 blocks x 256; wave handles 8 rows.
__global__ void rowstat_kernel(const __hip_bfloat16* __restrict__ featS,
                               const __hip_bfloat16* __restrict__ featT0,
                               const __hip_bfloat16* __restrict__ featT1,
                               const int* __restrict__ labels,
                               const float* __restrict__ gAll,
                               const int* __restrict__ cnt,
                               const float* __restrict__ Sarr,
                               float* __restrict__ lossAcc,
                               int* __restrict__ ticket,
                               float* __restrict__ out) {
    __shared__ float wpart[4];
    const int tid = threadIdx.x;
    const int wv  = tid >> 6;
    const int l   = tid & 63;
    const int waveid = blockIdx.x * 4 + wv;   // 0..2047
    float psum = 0.0f;

    for (int it = 0; it < 8; ++it) {
        int R = waveid * 8 + it;              // 0..16383
        int t = R >> 13;
        int i = R & (N_SIZE - 1);
        const __hip_bfloat16* f = (i < B_SIZE) ? featS + i * D_SIZE
                                : (t ? featT1 : featT0) + (i - B_SIZE) * D_SIZE;
        int lab = labels[i & (B_SIZE - 1)] & 127;
        short4v fb = *reinterpret_cast<const short4v*>(f + l * 4);
        float fx[4];
#pragma unroll
        for (int k = 0; k < 4; ++k) {
            unsigned int u = ((unsigned int)(unsigned short)fb[k]) << 16;
            fx[k] = __uint_as_float(u);
        }
        const float* gS = gAll + lab * 256 + l * 4;
        const float* gT = gAll + (1 + t) * 32768 + lab * 256 + l * 4;
        float dot = 0.f, aii = 0.f;
#pragma unroll
        for (int k = 0; k < 4; ++k) {
            dot += fx[k] * (gS[k] + gT[k]);
            aii += fx[k] * fx[k];
        }
#pragma unroll
        for (int m = 1; m < 64; m <<= 1) {
            dot += __shfl_xor(dot, m);
            aii += __shfl_xor(aii, m);
        }
        if (l == 0) {
            float S = Sarr[t * N_SIZE + i];
            float M = 2.0f * (float)cnt[lab] - 1.0f;
            float E = FAST_EXP2(LOG2E10 * aii);
            psum += logf(S - E) - 10.0f * (dot - aii) / M;
        }
    }
    if (l == 0) wpart[wv] = psum;
    __syncthreads();
    if (tid == 0) {
        atomicAdd(lossAcc, wpart[0] + wpart[1] + wpart[2] + wpart[3]);
        __threadfence();
        if (atomicAdd(ticket, 1) == 511) {
            float tot = atomicAdd(lossAcc, 0.0f);
            out[0] = tot / 16384.0f;
        }
    }
}

extern "C" void kernel_launch(void* const* d_in, const int* in_sizes, int n_in,
                              void* d_out, int out_size, void* d_ws, size_t ws_size,
                              hipStream_t stream) {
    const float* hs     = (const float*)d_in[0];
    const float* ht0    = (const float*)d_in[1];
    const float* ht1    = (const float*)d_in[2];
    const int*   labels = (const int*)d_in[3];

    char* ws = (char*)d_ws;
    float* Sarr    = (float*)(ws);
    float* lossAcc = (float*)(ws + 65536);
    int*   ticket  = (int*)(ws + 65540);
    int*   cnt     = (int*)(ws + 66048);
    int*   offv    = (int*)(ws + 66560);
    int*   idxS    = (int*)(ws + 67072);
    float* gAll    = (float*)(ws + 83968);
    __hip_bfloat16* featS  = (__hip_bfloat16*)(ws + 524288);
    __hip_bfloat16* featT0 = (__hip_bfloat16*)(ws + 524288 + 2097152);
    __hip_bfloat16* featT1 = (__hip_bfloat16*)(ws + 524288 + 2 * 2097152);

    norm_kernel<<<3072, 256, 0, stream>>>(hs, ht0, ht1, featS, (float*)ws,
                                          labels, cnt, offv, idxS);
    gvec_kernel<<<384, 256, 0, stream>>>(featS, cnt, offv, idxS, gAll);
    sim_kernel<<<512, 256, 0, stream>>>(featS, featT0, featT1, Sarr);
    rowstat_kernel<<<512, 256, 0, stream>>>(featS, featT0, featT1, labels, gAll, cnt,
                                            Sarr, lossAcc, ticket, (float*)d_out);
}